// Round 3
// baseline (13166.788 us; speedup 1.0000x reference)
//
#include <hip/hip_runtime.h>
#include <math.h>

#define N_NODES 100000
#define N_EDGES 1600000
#define IN_C 128
#define HID_C 128
#define OUT_C 64
#define NLAYERS 4
#define KSTEPS 10
#define ALPHA 0.1f
#define LN_EPS 1e-5f

#define SCAN_N (N_NODES + 1)
#define SCAN_BLOCKS ((SCAN_N + 1023) / 1024)     // 98
#define EP_CAP 2400000                            // 1.6M edges + <=7 pad/node
#define N_SHARD 8
#define SHARD_STRIDE ((size_t)N_NODES * 8)        // dwords per 16-channel shard

__device__ __forceinline__ float gelu_exact(float x) {
    return 0.5f * x * (1.0f + erff(x * 0.70710678118654752f));
}

// Pack two fp32 into bf16x2 (round-to-nearest-even). a -> low (ch 2l), b -> high.
__device__ __forceinline__ unsigned pack_bf16_rne(float a, float b) {
    unsigned ua = __float_as_uint(a);
    unsigned ub = __float_as_uint(b);
    ua = (ua + 0x7fffu + ((ua >> 16) & 1u)) >> 16;
    ub = (ub + 0x7fffu + ((ub >> 16) & 1u)) >> 16;
    return (ub << 16) | ua;
}
__device__ __forceinline__ float bf_lo(unsigned d) { return __uint_as_float(d << 16); }
__device__ __forceinline__ float bf_hi(unsigned d) { return __uint_as_float(d & 0xffff0000u); }

// ---------------------------------------------------------------------------
// CSR build: count in-degree per dst
__global__ void count_k(const int* __restrict__ dst, int* __restrict__ counts) {
    int e = blockIdx.x * blockDim.x + threadIdx.x;
    if (e < N_EDGES) atomicAdd(&counts[dst[e]], 1);
}

// scan1: per-block sums of padded (x8) counts
__global__ __launch_bounds__(1024) void scan1_k(const int* __restrict__ counts,
                                                int* __restrict__ bsum) {
    __shared__ int s[1024];
    int i = blockIdx.x * 1024 + threadIdx.x;
    int c = 0;
    if (i < N_NODES) c = (counts[i] + 7) & ~7;
    s[threadIdx.x] = c;
    __syncthreads();
    for (int off = 512; off; off >>= 1) {
        if (threadIdx.x < off) s[threadIdx.x] += s[threadIdx.x + off];
        __syncthreads();
    }
    if (threadIdx.x == 0) bsum[blockIdx.x] = s[0];
}

// scan2: exclusive scan of the 98 block sums
__global__ void scan2_k(int* __restrict__ bsum) {
    __shared__ int s[128];
    int t = threadIdx.x;
    s[t] = (t < SCAN_BLOCKS) ? bsum[t] : 0;
    __syncthreads();
    for (int off = 1; off < 128; off <<= 1) {
        int v = (t >= off) ? s[t - off] : 0;
        __syncthreads();
        s[t] += v;
        __syncthreads();
    }
    if (t < SCAN_BLOCKS) bsum[t] = (t == 0) ? 0 : s[t - 1];
}

// scan3: per-block exclusive scan + block offset -> row_off / fill_pos
__global__ __launch_bounds__(1024) void scan3_k(const int* __restrict__ counts,
                                                const int* __restrict__ bsum,
                                                int* __restrict__ row_off,
                                                int* __restrict__ fill_pos) {
    __shared__ int s[1024];
    int i = blockIdx.x * 1024 + threadIdx.x;
    int c = 0;
    if (i < N_NODES) c = (counts[i] + 7) & ~7;
    s[threadIdx.x] = c;
    __syncthreads();
    for (int off = 1; off < 1024; off <<= 1) {
        int v = (threadIdx.x >= off) ? s[threadIdx.x - off] : 0;
        __syncthreads();
        s[threadIdx.x] += v;
        __syncthreads();
    }
    if (i <= N_NODES) {
        int excl = s[threadIdx.x] - c + bsum[blockIdx.x];
        row_off[i] = excl;
        fill_pos[i] = excl;
    }
}

// Bucket edges by dst; pack (src*8 [dword offset within a shard], (1-alpha)*w).
// Pad slots stay (0,0.0f) from the ep memset -> gather row 0 * 0 -> no-op.
__global__ void bucket_k(const int* __restrict__ src, const int* __restrict__ dst,
                         const float* __restrict__ w,
                         int* __restrict__ fill_pos, int2* __restrict__ ep) {
    int e = blockIdx.x * blockDim.x + threadIdx.x;
    if (e >= N_EDGES) return;
    int d = dst[e];
    int pos = atomicAdd(&fill_pos[d], 1);
    float ws = (1.0f - ALPHA) * w[e];
    ep[pos] = make_int2(src[e] << 3, __float_as_int(ws));
}

// ---------------------------------------------------------------------------
// Encoder: H(bf16, SHARDED layout) = gelu(LN(x @ Wenc^T)).
// Shard s holds channels [16s,16s+16) for all nodes: H[s*STRIDE + n*8 + m].
__global__ __launch_bounds__(1024) void encoder_k(
        const float* __restrict__ x, const float* __restrict__ Wenc,
        const float* __restrict__ gamma, const float* __restrict__ beta,
        unsigned* __restrict__ H) {
    __shared__ float WT[IN_C * 130];           // WT[k*130 + c]
    __shared__ float XS[16][512];              // per-wave 4-row x tile
    for (int i = threadIdx.x; i < IN_C * HID_C; i += 1024) {
        int c = i >> 7, k = i & 127;
        WT[k * 130 + c] = Wenc[i];
    }
    __syncthreads();
    int lane = threadIdx.x & 63;
    int wid  = threadIdx.x >> 6;
    const float2* WT2 = (const float2*)WT;     // index k*65 + lane
    float2 gb = ((const float2*)gamma)[lane];
    float2 bb = ((const float2*)beta)[lane];
    int wstride = gridDim.x * 16;
    float* xs = XS[wid];
    // per-lane shard store base: lane holds channel pair (2l,2l+1) -> shard l>>3, dword l&7
    unsigned* Hl = H + (size_t)(lane >> 3) * SHARD_STRIDE + (lane & 7);
    for (int grp = blockIdx.x * 16 + wid; grp * 4 < N_NODES; grp += wstride) {
        int r0 = grp * 4;
        const float4* xr = (const float4*)(x + (size_t)r0 * IN_C);
        ((float4*)xs)[lane]      = xr[lane];        // rows r0, r0+1
        ((float4*)xs)[64 + lane] = xr[64 + lane];   // rows r0+2, r0+3
        __builtin_amdgcn_wave_barrier();            // wave-private: no block barrier
        float a0x = 0, a0y = 0, a1x = 0, a1y = 0;
        float a2x = 0, a2y = 0, a3x = 0, a3y = 0;
        const float4* xs4 = (const float4*)xs;
#pragma unroll 4
        for (int k4 = 0; k4 < 32; ++k4) {
            float4 xv0 = xs4[k4];
            float4 xv1 = xs4[32 + k4];
            float4 xv2 = xs4[64 + k4];
            float4 xv3 = xs4[96 + k4];
            int k = k4 * 4;
            float2 w0 = WT2[(k + 0) * 65 + lane];
            float2 w1 = WT2[(k + 1) * 65 + lane];
            float2 w2 = WT2[(k + 2) * 65 + lane];
            float2 w3 = WT2[(k + 3) * 65 + lane];
#define ENC_ROW(ax, ay, xv)                                      \
            ax = fmaf(xv.x, w0.x, ax); ay = fmaf(xv.x, w0.y, ay); \
            ax = fmaf(xv.y, w1.x, ax); ay = fmaf(xv.y, w1.y, ay); \
            ax = fmaf(xv.z, w2.x, ax); ay = fmaf(xv.z, w2.y, ay); \
            ax = fmaf(xv.w, w3.x, ax); ay = fmaf(xv.w, w3.y, ay);
            ENC_ROW(a0x, a0y, xv0)
            ENC_ROW(a1x, a1y, xv1)
            ENC_ROW(a2x, a2y, xv2)
            ENC_ROW(a3x, a3y, xv3)
#undef ENC_ROW
        }
        __builtin_amdgcn_wave_barrier();
#define ENC_EPI(ax, ay, row)                                               \
        {                                                                   \
            float sum = ax + ay;                                            \
            for (int off = 32; off; off >>= 1) sum += __shfl_xor(sum, off); \
            float mu = sum * (1.0f / 128.0f);                               \
            float d0 = ax - mu, d1 = ay - mu;                               \
            float vs = d0 * d0 + d1 * d1;                                   \
            for (int off = 32; off; off >>= 1) vs += __shfl_xor(vs, off);   \
            float inv = rsqrtf(vs * (1.0f / 128.0f) + LN_EPS);              \
            float o0 = gelu_exact(gb.x * d0 * inv + bb.x);                  \
            float o1 = gelu_exact(gb.y * d1 * inv + bb.y);                  \
            Hl[(size_t)(row) * 8] = pack_bf16_rne(o0, o1);                  \
        }
        ENC_EPI(a0x, a0y, r0)
        ENC_EPI(a1x, a1y, r0 + 1)
        ENC_EPI(a2x, a2y, r0 + 2)
        ENC_EPI(a3x, a3y, r0 + 3)
#undef ENC_EPI
    }
}

// ---------------------------------------------------------------------------
// One APPNP step (pull), bf16 features, XCD channel-sharded.
// shard = blockIdx & 7 -> lands on one XCD (round-robin dispatch), whose
// gathers then live in a private 3.2 MB region resident in that XCD's 4 MiB L2.
// Wave per (node, shard): 8 edge-slots x 8 lanes; lane (slot,m) gathers dword m
// of edge slot's src-row chunk (32 B contiguous per slot). ep/x0/zout use
// non-temporal hints so streams don't evict the resident shard.
__global__ __launch_bounds__(256) void prop_k(
        const unsigned* __restrict__ zin, const unsigned* __restrict__ x0,
        const int* __restrict__ row_off, const int2* __restrict__ ep,
        unsigned* __restrict__ zout) {
    int shard = blockIdx.x & 7;
    int gw = (blockIdx.x >> 3) * 4 + (threadIdx.x >> 6);   // node id
    int lane = threadIdx.x & 63;
    int slot = lane >> 3;          // edge slot within round (0..7)
    int m    = lane & 7;           // dword within 32B chunk
    const unsigned* zs = zin + (size_t)shard * SHARD_STRIDE;
    int s0 = row_off[gw];
    int s1 = row_off[gw + 1];      // padded degree (x8)
    unsigned xd = __builtin_nontemporal_load(
        x0 + (size_t)shard * SHARD_STRIDE + (size_t)gw * 8 + m);
    float sx = 0.f, sy = 0.f;
    for (int base = s0; base < s1; base += 8) {
        unsigned long long q = __builtin_nontemporal_load(
            (const unsigned long long*)(ep + base + slot));
        int   off = (int)(unsigned)(q & 0xffffffffu);   // src*8 (dword offset)
        float w   = __uint_as_float((unsigned)(q >> 32));
        unsigned d = zs[off + m];                        // L2-resident gather
        sx = fmaf(w, bf_lo(d), sx);
        sy = fmaf(w, bf_hi(d), sy);
    }
    // reduce across the 8 edge slots (lane bits 3..5)
    sx += __shfl_xor(sx, 8);  sy += __shfl_xor(sy, 8);
    sx += __shfl_xor(sx, 16); sy += __shfl_xor(sy, 16);
    sx += __shfl_xor(sx, 32); sy += __shfl_xor(sy, 32);
    float zx = fmaf(ALPHA, bf_lo(xd), sx);
    float zy = fmaf(ALPHA, bf_hi(xd), sy);
    if (lane < 8) {
        __builtin_nontemporal_store(pack_bf16_rne(zx, zy),
            zout + (size_t)shard * SHARD_STRIDE + (size_t)gw * 8 + lane);
    }
}

// ---------------------------------------------------------------------------
// gelu + LayerNorm over full 128-channel rows of a sharded buffer -> Hout.
// Wave handles 8 nodes: lane (j,m): node n0+j, dword m of each shard.
// All 8 shard loads are fully coalesced (256 B per instruction per wave).
__global__ __launch_bounds__(256) void lnact_k(
        const unsigned* __restrict__ z, unsigned* __restrict__ Hout,
        const float* __restrict__ gamma, const float* __restrict__ beta) {
    int lane = threadIdx.x & 63;
    int w = threadIdx.x >> 6;
    int m = lane & 7;
    int n = blockIdx.x * 32 + w * 8 + (lane >> 3);
    unsigned v[8];
#pragma unroll
    for (int s = 0; s < 8; ++s)
        v[s] = z[(size_t)s * SHARD_STRIDE + (size_t)n * 8 + m];
    float h[16];
#pragma unroll
    for (int s = 0; s < 8; ++s) {
        h[2 * s]     = gelu_exact(bf_lo(v[s]));
        h[2 * s + 1] = gelu_exact(bf_hi(v[s]));
    }
    float sum = 0.f;
#pragma unroll
    for (int i = 0; i < 16; ++i) sum += h[i];
    sum += __shfl_xor(sum, 1);
    sum += __shfl_xor(sum, 2);
    sum += __shfl_xor(sum, 4);
    float mu = sum * (1.0f / 128.0f);
    float d[16];
    float vs = 0.f;
#pragma unroll
    for (int i = 0; i < 16; ++i) { d[i] = h[i] - mu; vs += d[i] * d[i]; }
    vs += __shfl_xor(vs, 1);
    vs += __shfl_xor(vs, 2);
    vs += __shfl_xor(vs, 4);
    float inv = rsqrtf(vs * (1.0f / 128.0f) + LN_EPS);
    const float2* g2 = (const float2*)gamma;
    const float2* b2 = (const float2*)beta;
#pragma unroll
    for (int s = 0; s < 8; ++s) {
        float2 gb = g2[s * 8 + m];
        float2 bb = b2[s * 8 + m];
        unsigned od = pack_bf16_rne(gb.x * d[2 * s] * inv + bb.x,
                                    gb.y * d[2 * s + 1] * inv + bb.y);
        Hout[(size_t)s * SHARD_STRIDE + (size_t)n * 8 + m] = od;
    }
}

// ---------------------------------------------------------------------------
// Decoder: out(fp32) = H(bf16, sharded) @ Wdec^T -> [N, 64].
__global__ __launch_bounds__(1024) void decoder_k(
        const unsigned* __restrict__ H, const float* __restrict__ Wdec,
        float* __restrict__ out) {
    __shared__ float WT[HID_C * 65];           // WT[k*65 + o]
    __shared__ unsigned XS[16][256];
    for (int i = threadIdx.x; i < OUT_C * HID_C; i += 1024) {
        int o = i >> 7, k = i & 127;
        WT[k * 65 + o] = Wdec[i];
    }
    __syncthreads();
    int lane = threadIdx.x & 63;
    int wid  = threadIdx.x >> 6;
    int wstride = gridDim.x * 16;
    unsigned* xs = XS[wid];
    // sharded load base: channel-pair index == lane (shard lane>>3, dword lane&7)
    const unsigned* Hl = H + (size_t)(lane >> 3) * SHARD_STRIDE + (lane & 7);
    for (int grp = blockIdx.x * 16 + wid; grp * 4 < N_NODES; grp += wstride) {
        int r0 = grp * 4;
        xs[lane]       = Hl[(size_t)(r0 + 0) * 8];
        xs[64 + lane]  = Hl[(size_t)(r0 + 1) * 8];
        xs[128 + lane] = Hl[(size_t)(r0 + 2) * 8];
        xs[192 + lane] = Hl[(size_t)(r0 + 3) * 8];
        __builtin_amdgcn_wave_barrier();
        float a0 = 0, a1 = 0, a2 = 0, a3 = 0;
#pragma unroll 4
        for (int k2 = 0; k2 < 64; ++k2) {      // channel-pair index
            float w0 = WT[(2 * k2) * 65 + lane];
            float w1 = WT[(2 * k2 + 1) * 65 + lane];
            unsigned u0 = xs[k2];
            unsigned u1 = xs[64 + k2];
            unsigned u2 = xs[128 + k2];
            unsigned u3 = xs[192 + k2];
            a0 = fmaf(bf_lo(u0), w0, a0); a0 = fmaf(bf_hi(u0), w1, a0);
            a1 = fmaf(bf_lo(u1), w0, a1); a1 = fmaf(bf_hi(u1), w1, a1);
            a2 = fmaf(bf_lo(u2), w0, a2); a2 = fmaf(bf_hi(u2), w1, a2);
            a3 = fmaf(bf_lo(u3), w0, a3); a3 = fmaf(bf_hi(u3), w1, a3);
        }
        __builtin_amdgcn_wave_barrier();
        out[(size_t)r0 * OUT_C + lane]       = a0;
        out[(size_t)(r0 + 1) * OUT_C + lane] = a1;
        out[(size_t)(r0 + 2) * OUT_C + lane] = a2;
        out[(size_t)(r0 + 3) * OUT_C + lane] = a3;
    }
}

// ---------------------------------------------------------------------------
extern "C" void kernel_launch(void* const* d_in, const int* in_sizes, int n_in,
                              void* d_out, int out_size, void* d_ws, size_t ws_size,
                              hipStream_t stream) {
    const float* x     = (const float*)d_in[0];
    const int*   ei    = (const int*)d_in[1];   // [2, E] int32
    const float* ew    = (const float*)d_in[2];
    const float* Wenc  = (const float*)d_in[3];
    const float* Wdec  = (const float*)d_in[4];
    const float* gamma = (const float*)d_in[5];
    const float* beta  = (const float*)d_in[6];
    float* out = (float*)d_out;

    const int* src = ei;
    const int* dst = ei + N_EDGES;

    char* p = (char*)d_ws;
    auto carve = [&](size_t bytes) -> void* {
        void* r = (void*)p;
        p += (bytes + 255) & ~(size_t)255;
        return r;
    };
    int*  counts  = (int*)carve(SCAN_N * sizeof(int));
    int*  fillpos = (int*)carve(SCAN_N * sizeof(int));
    int*  row_off = (int*)carve(SCAN_N * sizeof(int));
    int*  bsum    = (int*)carve(SCAN_BLOCKS * sizeof(int));
    int2* ep      = (int2*)carve((size_t)EP_CAP * sizeof(int2));
    unsigned* H  = (unsigned*)carve((size_t)N_NODES * 64 * sizeof(unsigned));
    unsigned* ZA = (unsigned*)carve((size_t)N_NODES * 64 * sizeof(unsigned));
    unsigned* ZB = (unsigned*)carve((size_t)N_NODES * 64 * sizeof(unsigned));

    // CSR build (per launch; deterministic work each call)
    hipMemsetAsync(counts, 0, SCAN_N * sizeof(int), stream);
    hipMemsetAsync(ep, 0, (size_t)EP_CAP * sizeof(int2), stream);  // pads -> (0,0)
    count_k<<<(N_EDGES + 255) / 256, 256, 0, stream>>>(dst, counts);
    scan1_k<<<SCAN_BLOCKS, 1024, 0, stream>>>(counts, bsum);
    scan2_k<<<1, 128, 0, stream>>>(bsum);
    scan3_k<<<SCAN_BLOCKS, 1024, 0, stream>>>(counts, bsum, row_off, fillpos);
    bucket_k<<<(N_EDGES + 255) / 256, 256, 0, stream>>>(src, dst, ew, fillpos, ep);

    // Encoder (writes sharded H)
    encoder_k<<<512, 1024, 0, stream>>>(x, Wenc, gamma, beta, H);

    const int prop_blocks = (N_NODES / 4) * N_SHARD;   // wave per (node, shard)
    unsigned* bufs[2] = {ZA, ZB};
    for (int l = 0; l < NLAYERS; ++l) {
        const unsigned* zin = H;                  // x0 = H (layer input)
        for (int k = 0; k < KSTEPS; ++k) {
            unsigned* zout = bufs[k & 1];
            prop_k<<<prop_blocks, 256, 0, stream>>>(zin, H, row_off, ep, zout);
            zin = zout;
        }
        // gelu + LN on the K-step result -> new H (also final H for decoder)
        lnact_k<<<N_NODES / 32, 256, 0, stream>>>(bufs[1], H, gamma, beta);
    }

    decoder_k<<<512, 1024, 0, stream>>>(H, Wdec, out);
}

// Round 4
// 2811.765 us; speedup vs baseline: 4.6827x; 4.6827x over previous
//
#include <hip/hip_runtime.h>
#include <math.h>

#define N_NODES 100000
#define N_EDGES 1600000
#define IN_C 128
#define HID_C 128
#define OUT_C 64
#define NLAYERS 4
#define KSTEPS 10
#define ALPHA 0.1f
#define LN_EPS 1e-5f

#define SCAN_N (N_NODES + 1)
#define SCAN_BLOCKS ((SCAN_N + 1023) / 1024)     // 98
#define EP_CAP 2400000                            // 1.6M edges + <=7 pad/node
#define BUCKET_PASSES 8
#define BUCKET_RANGE ((N_NODES + BUCKET_PASSES - 1) / BUCKET_PASSES)

__device__ __forceinline__ float gelu_exact(float x) {
    return 0.5f * x * (1.0f + erff(x * 0.70710678118654752f));
}

// Pack two fp32 into bf16x2 (round-to-nearest-even). a -> low (ch 2l), b -> high.
__device__ __forceinline__ unsigned pack_bf16_rne(float a, float b) {
    unsigned ua = __float_as_uint(a);
    unsigned ub = __float_as_uint(b);
    ua = (ua + 0x7fffu + ((ua >> 16) & 1u)) >> 16;
    ub = (ub + 0x7fffu + ((ub >> 16) & 1u)) >> 16;
    return (ub << 16) | ua;
}
__device__ __forceinline__ float bf_lo(unsigned d) { return __uint_as_float(d << 16); }
__device__ __forceinline__ float bf_hi(unsigned d) { return __uint_as_float(d & 0xffff0000u); }

// ---------------------------------------------------------------------------
// CSR build: count in-degree per dst
__global__ void count_k(const int* __restrict__ dst, int* __restrict__ counts) {
    int e = blockIdx.x * blockDim.x + threadIdx.x;
    if (e < N_EDGES) atomicAdd(&counts[dst[e]], 1);
}

// scan1: per-block sums of padded (x8) counts
__global__ __launch_bounds__(1024) void scan1_k(const int* __restrict__ counts,
                                                int* __restrict__ bsum) {
    __shared__ int s[1024];
    int i = blockIdx.x * 1024 + threadIdx.x;
    int c = 0;
    if (i < N_NODES) c = (counts[i] + 7) & ~7;
    s[threadIdx.x] = c;
    __syncthreads();
    for (int off = 512; off; off >>= 1) {
        if (threadIdx.x < off) s[threadIdx.x] += s[threadIdx.x + off];
        __syncthreads();
    }
    if (threadIdx.x == 0) bsum[blockIdx.x] = s[0];
}

// scan2: exclusive scan of the 98 block sums
__global__ void scan2_k(int* __restrict__ bsum) {
    __shared__ int s[128];
    int t = threadIdx.x;
    s[t] = (t < SCAN_BLOCKS) ? bsum[t] : 0;
    __syncthreads();
    for (int off = 1; off < 128; off <<= 1) {
        int v = (t >= off) ? s[t - off] : 0;
        __syncthreads();
        s[t] += v;
        __syncthreads();
    }
    if (t < SCAN_BLOCKS) bsum[t] = (t == 0) ? 0 : s[t - 1];
}

// scan3: per-block exclusive scan + block offset -> row_off / fill_pos
__global__ __launch_bounds__(1024) void scan3_k(const int* __restrict__ counts,
                                                const int* __restrict__ bsum,
                                                int* __restrict__ row_off,
                                                int* __restrict__ fill_pos) {
    __shared__ int s[1024];
    int i = blockIdx.x * 1024 + threadIdx.x;
    int c = 0;
    if (i < N_NODES) c = (counts[i] + 7) & ~7;
    s[threadIdx.x] = c;
    __syncthreads();
    for (int off = 1; off < 1024; off <<= 1) {
        int v = (threadIdx.x >= off) ? s[threadIdx.x - off] : 0;
        __syncthreads();
        s[threadIdx.x] += v;
        __syncthreads();
    }
    if (i <= N_NODES) {
        int excl = s[threadIdx.x] - c + bsum[blockIdx.x];
        row_off[i] = excl;
        fill_pos[i] = excl;
    }
}

// Bucket edges by dst; pack (src*64 [dword offset of bf16x2 row], (1-alpha)*w).
// Pad slots stay (0,0.0f) from the ep memset -> gather row 0 * 0 -> no-op.
// Range-restricted: pass p handles dst in [lo,hi) so scatter writes stay in a
// ~2.4 MB window that accumulates whole dirty lines in L2 before eviction
// (full-range version showed 99 MB WRITE_SIZE for a 12.8 MB scatter).
__global__ void bucket_k(const int* __restrict__ src, const int* __restrict__ dst,
                         const float* __restrict__ w,
                         int* __restrict__ fill_pos, int2* __restrict__ ep,
                         int lo, int hi) {
    int e = blockIdx.x * blockDim.x + threadIdx.x;
    if (e >= N_EDGES) return;
    int d = dst[e];
    if (d < lo || d >= hi) return;
    int pos = atomicAdd(&fill_pos[d], 1);
    float ws = (1.0f - ALPHA) * w[e];
    ep[pos] = make_int2(src[e] << 6, __float_as_int(ws));
}

// ---------------------------------------------------------------------------
// Encoder: H(bf16) = gelu(LN(x @ Wenc^T)).
// block=1024 (16 waves); wave: 4 rows; lane holds channel pair (2l, 2l+1).
__global__ __launch_bounds__(1024) void encoder_k(
        const float* __restrict__ x, const float* __restrict__ Wenc,
        const float* __restrict__ gamma, const float* __restrict__ beta,
        unsigned* __restrict__ H) {
    __shared__ float WT[IN_C * 130];           // WT[k*130 + c]
    __shared__ float XS[16][512];              // per-wave 4-row x tile
    for (int i = threadIdx.x; i < IN_C * HID_C; i += 1024) {
        int c = i >> 7, k = i & 127;
        WT[k * 130 + c] = Wenc[i];
    }
    __syncthreads();
    int lane = threadIdx.x & 63;
    int wid  = threadIdx.x >> 6;
    const float2* WT2 = (const float2*)WT;     // index k*65 + lane
    float2 gb = ((const float2*)gamma)[lane];
    float2 bb = ((const float2*)beta)[lane];
    int wstride = gridDim.x * 16;
    float* xs = XS[wid];
    for (int grp = blockIdx.x * 16 + wid; grp * 4 < N_NODES; grp += wstride) {
        int r0 = grp * 4;
        const float4* xr = (const float4*)(x + (size_t)r0 * IN_C);
        ((float4*)xs)[lane]      = xr[lane];        // rows r0, r0+1
        ((float4*)xs)[64 + lane] = xr[64 + lane];   // rows r0+2, r0+3
        __builtin_amdgcn_wave_barrier();            // wave-private: no block barrier
        float a0x = 0, a0y = 0, a1x = 0, a1y = 0;
        float a2x = 0, a2y = 0, a3x = 0, a3y = 0;
        const float4* xs4 = (const float4*)xs;
#pragma unroll 4
        for (int k4 = 0; k4 < 32; ++k4) {
            float4 xv0 = xs4[k4];
            float4 xv1 = xs4[32 + k4];
            float4 xv2 = xs4[64 + k4];
            float4 xv3 = xs4[96 + k4];
            int k = k4 * 4;
            float2 w0 = WT2[(k + 0) * 65 + lane];
            float2 w1 = WT2[(k + 1) * 65 + lane];
            float2 w2 = WT2[(k + 2) * 65 + lane];
            float2 w3 = WT2[(k + 3) * 65 + lane];
#define ENC_ROW(ax, ay, xv)                                      \
            ax = fmaf(xv.x, w0.x, ax); ay = fmaf(xv.x, w0.y, ay); \
            ax = fmaf(xv.y, w1.x, ax); ay = fmaf(xv.y, w1.y, ay); \
            ax = fmaf(xv.z, w2.x, ax); ay = fmaf(xv.z, w2.y, ay); \
            ax = fmaf(xv.w, w3.x, ax); ay = fmaf(xv.w, w3.y, ay);
            ENC_ROW(a0x, a0y, xv0)
            ENC_ROW(a1x, a1y, xv1)
            ENC_ROW(a2x, a2y, xv2)
            ENC_ROW(a3x, a3y, xv3)
#undef ENC_ROW
        }
        __builtin_amdgcn_wave_barrier();
#define ENC_EPI(ax, ay, row)                                               \
        {                                                                   \
            float sum = ax + ay;                                            \
            for (int off = 32; off; off >>= 1) sum += __shfl_xor(sum, off); \
            float mu = sum * (1.0f / 128.0f);                               \
            float d0 = ax - mu, d1 = ay - mu;                               \
            float vs = d0 * d0 + d1 * d1;                                   \
            for (int off = 32; off; off >>= 1) vs += __shfl_xor(vs, off);   \
            float inv = rsqrtf(vs * (1.0f / 128.0f) + LN_EPS);              \
            float o0 = gelu_exact(gb.x * d0 * inv + bb.x);                  \
            float o1 = gelu_exact(gb.y * d1 * inv + bb.y);                  \
            H[(size_t)(row)*64 + lane] = pack_bf16_rne(o0, o1);             \
        }
        ENC_EPI(a0x, a0y, r0)
        ENC_EPI(a1x, a1y, r0 + 1)
        ENC_EPI(a2x, a2y, r0 + 2)
        ENC_EPI(a3x, a3y, r0 + 3)
#undef ENC_EPI
    }
}

// ---------------------------------------------------------------------------
// One APPNP step (pull), bf16 features. Wave per node; lane holds channel pair
// (2l, 2l+1) as one bf16x2 dword -> 256 B/row gathers.
// Edge (offset, weight) broadcast via v_readlane -> SGPR (saddr-form loads,
// zero per-edge address VALU, no DS traffic). Inner block unrolled 16-deep so
// SIXTEEN independent row gathers are in flight before the first waitcnt
// (MLP probe: 8-deep variants plateau at ~62 us/step).
// Accumulate fp32; store bf16 (RNE). fuse_ln: gelu+LN on the last K-step.
__global__ __launch_bounds__(256) void prop_k(
        const unsigned* __restrict__ zin, const unsigned* __restrict__ x0,
        const int* __restrict__ row_off, const int2* __restrict__ ep,
        unsigned* __restrict__ zout, int fuse_ln,
        const float* __restrict__ gamma, const float* __restrict__ beta) {
    int gw = (blockIdx.x * 256 + threadIdx.x) >> 6;   // node id
    if (gw >= N_NODES) return;
    int lane = threadIdx.x & 63;
    int s0 = row_off[gw];
    int s1 = row_off[gw + 1];                          // padded degree (x8)
    unsigned xd = x0[(size_t)gw * 64 + lane];          // prefetch alpha-term row
    float sx = 0.f, sy = 0.f;
    for (int base = s0; base < s1; base += 64) {
        int cnt = min(64, s1 - base);                  // multiple of 8
        int2 p = make_int2(0, 0);
        if (lane < cnt) p = ep[base + lane];
        int j = 0;
#define EDGE(k, ov, wv)                                                     \
        int   ov = __builtin_amdgcn_readlane(p.x, j + k);                   \
        float wv = __uint_as_float(                                         \
            (unsigned)__builtin_amdgcn_readlane(p.y, j + k));
        for (; j + 16 <= cnt; j += 16) {
            EDGE(0,  o0,  w0)  EDGE(1,  o1,  w1)  EDGE(2,  o2,  w2)
            EDGE(3,  o3,  w3)  EDGE(4,  o4,  w4)  EDGE(5,  o5,  w5)
            EDGE(6,  o6,  w6)  EDGE(7,  o7,  w7)  EDGE(8,  o8,  w8)
            EDGE(9,  o9,  w9)  EDGE(10, o10, w10) EDGE(11, o11, w11)
            EDGE(12, o12, w12) EDGE(13, o13, w13) EDGE(14, o14, w14)
            EDGE(15, o15, w15)
            unsigned d0  = zin[o0  + lane];
            unsigned d1  = zin[o1  + lane];
            unsigned d2  = zin[o2  + lane];
            unsigned d3  = zin[o3  + lane];
            unsigned d4  = zin[o4  + lane];
            unsigned d5  = zin[o5  + lane];
            unsigned d6  = zin[o6  + lane];
            unsigned d7  = zin[o7  + lane];
            unsigned d8  = zin[o8  + lane];
            unsigned d9  = zin[o9  + lane];
            unsigned d10 = zin[o10 + lane];
            unsigned d11 = zin[o11 + lane];
            unsigned d12 = zin[o12 + lane];
            unsigned d13 = zin[o13 + lane];
            unsigned d14 = zin[o14 + lane];
            unsigned d15 = zin[o15 + lane];
            sx = fmaf(w0,  bf_lo(d0),  sx); sy = fmaf(w0,  bf_hi(d0),  sy);
            sx = fmaf(w1,  bf_lo(d1),  sx); sy = fmaf(w1,  bf_hi(d1),  sy);
            sx = fmaf(w2,  bf_lo(d2),  sx); sy = fmaf(w2,  bf_hi(d2),  sy);
            sx = fmaf(w3,  bf_lo(d3),  sx); sy = fmaf(w3,  bf_hi(d3),  sy);
            sx = fmaf(w4,  bf_lo(d4),  sx); sy = fmaf(w4,  bf_hi(d4),  sy);
            sx = fmaf(w5,  bf_lo(d5),  sx); sy = fmaf(w5,  bf_hi(d5),  sy);
            sx = fmaf(w6,  bf_lo(d6),  sx); sy = fmaf(w6,  bf_hi(d6),  sy);
            sx = fmaf(w7,  bf_lo(d7),  sx); sy = fmaf(w7,  bf_hi(d7),  sy);
            sx = fmaf(w8,  bf_lo(d8),  sx); sy = fmaf(w8,  bf_hi(d8),  sy);
            sx = fmaf(w9,  bf_lo(d9),  sx); sy = fmaf(w9,  bf_hi(d9),  sy);
            sx = fmaf(w10, bf_lo(d10), sx); sy = fmaf(w10, bf_hi(d10), sy);
            sx = fmaf(w11, bf_lo(d11), sx); sy = fmaf(w11, bf_hi(d11), sy);
            sx = fmaf(w12, bf_lo(d12), sx); sy = fmaf(w12, bf_hi(d12), sy);
            sx = fmaf(w13, bf_lo(d13), sx); sy = fmaf(w13, bf_hi(d13), sy);
            sx = fmaf(w14, bf_lo(d14), sx); sy = fmaf(w14, bf_hi(d14), sy);
            sx = fmaf(w15, bf_lo(d15), sx); sy = fmaf(w15, bf_hi(d15), sy);
        }
        if (j < cnt) {                                 // exactly 8 remain
            EDGE(0, o0, w0) EDGE(1, o1, w1) EDGE(2, o2, w2) EDGE(3, o3, w3)
            EDGE(4, o4, w4) EDGE(5, o5, w5) EDGE(6, o6, w6) EDGE(7, o7, w7)
            unsigned d0 = zin[o0 + lane];
            unsigned d1 = zin[o1 + lane];
            unsigned d2 = zin[o2 + lane];
            unsigned d3 = zin[o3 + lane];
            unsigned d4 = zin[o4 + lane];
            unsigned d5 = zin[o5 + lane];
            unsigned d6 = zin[o6 + lane];
            unsigned d7 = zin[o7 + lane];
            sx = fmaf(w0, bf_lo(d0), sx); sy = fmaf(w0, bf_hi(d0), sy);
            sx = fmaf(w1, bf_lo(d1), sx); sy = fmaf(w1, bf_hi(d1), sy);
            sx = fmaf(w2, bf_lo(d2), sx); sy = fmaf(w2, bf_hi(d2), sy);
            sx = fmaf(w3, bf_lo(d3), sx); sy = fmaf(w3, bf_hi(d3), sy);
            sx = fmaf(w4, bf_lo(d4), sx); sy = fmaf(w4, bf_hi(d4), sy);
            sx = fmaf(w5, bf_lo(d5), sx); sy = fmaf(w5, bf_hi(d5), sy);
            sx = fmaf(w6, bf_lo(d6), sx); sy = fmaf(w6, bf_hi(d6), sy);
            sx = fmaf(w7, bf_lo(d7), sx); sy = fmaf(w7, bf_hi(d7), sy);
        }
#undef EDGE
    }
    float zx = fmaf(ALPHA, bf_lo(xd), sx);
    float zy = fmaf(ALPHA, bf_hi(xd), sy);
    unsigned od;
    if (fuse_ln) {
        float h0 = gelu_exact(zx);
        float h1 = gelu_exact(zy);
        float sum = h0 + h1;
        for (int off = 32; off; off >>= 1) sum += __shfl_xor(sum, off);
        float mu = sum * (1.0f / 128.0f);
        float d0 = h0 - mu, d1 = h1 - mu;
        float vs = d0 * d0 + d1 * d1;
        for (int off = 32; off; off >>= 1) vs += __shfl_xor(vs, off);
        float inv = rsqrtf(vs * (1.0f / 128.0f) + LN_EPS);
        float2 gb = ((const float2*)gamma)[lane];
        float2 bb = ((const float2*)beta)[lane];
        od = pack_bf16_rne(gb.x * d0 * inv + bb.x, gb.y * d1 * inv + bb.y);
    } else {
        od = pack_bf16_rne(zx, zy);
    }
    zout[(size_t)gw * 64 + lane] = od;
}

// ---------------------------------------------------------------------------
// Decoder: out(fp32) = H(bf16) @ Wdec^T -> [N, 64].
__global__ __launch_bounds__(1024) void decoder_k(
        const unsigned* __restrict__ H, const float* __restrict__ Wdec,
        float* __restrict__ out) {
    __shared__ float WT[HID_C * 65];           // WT[k*65 + o]
    __shared__ unsigned XS[16][256];
    for (int i = threadIdx.x; i < OUT_C * HID_C; i += 1024) {
        int o = i >> 7, k = i & 127;
        WT[k * 65 + o] = Wdec[i];
    }
    __syncthreads();
    int lane = threadIdx.x & 63;
    int wid  = threadIdx.x >> 6;
    int wstride = gridDim.x * 16;
    unsigned* xs = XS[wid];
    for (int grp = blockIdx.x * 16 + wid; grp * 4 < N_NODES; grp += wstride) {
        int r0 = grp * 4;
        const unsigned* hp = H + (size_t)r0 * 64;
        xs[lane]       = hp[lane];
        xs[64 + lane]  = hp[64 + lane];
        xs[128 + lane] = hp[128 + lane];
        xs[192 + lane] = hp[192 + lane];
        __builtin_amdgcn_wave_barrier();
        float a0 = 0, a1 = 0, a2 = 0, a3 = 0;
#pragma unroll 4
        for (int k2 = 0; k2 < 64; ++k2) {      // channel-pair index
            float w0 = WT[(2 * k2) * 65 + lane];
            float w1 = WT[(2 * k2 + 1) * 65 + lane];
            unsigned u0 = xs[k2];
            unsigned u1 = xs[64 + k2];
            unsigned u2 = xs[128 + k2];
            unsigned u3 = xs[192 + k2];
            a0 = fmaf(bf_lo(u0), w0, a0); a0 = fmaf(bf_hi(u0), w1, a0);
            a1 = fmaf(bf_lo(u1), w0, a1); a1 = fmaf(bf_hi(u1), w1, a1);
            a2 = fmaf(bf_lo(u2), w0, a2); a2 = fmaf(bf_hi(u2), w1, a2);
            a3 = fmaf(bf_lo(u3), w0, a3); a3 = fmaf(bf_hi(u3), w1, a3);
        }
        __builtin_amdgcn_wave_barrier();
        out[(size_t)r0 * OUT_C + lane]       = a0;
        out[(size_t)(r0 + 1) * OUT_C + lane] = a1;
        out[(size_t)(r0 + 2) * OUT_C + lane] = a2;
        out[(size_t)(r0 + 3) * OUT_C + lane] = a3;
    }
}

// ---------------------------------------------------------------------------
extern "C" void kernel_launch(void* const* d_in, const int* in_sizes, int n_in,
                              void* d_out, int out_size, void* d_ws, size_t ws_size,
                              hipStream_t stream) {
    const float* x     = (const float*)d_in[0];
    const int*   ei    = (const int*)d_in[1];   // [2, E] int32
    const float* ew    = (const float*)d_in[2];
    const float* Wenc  = (const float*)d_in[3];
    const float* Wdec  = (const float*)d_in[4];
    const float* gamma = (const float*)d_in[5];
    const float* beta  = (const float*)d_in[6];
    float* out = (float*)d_out;

    const int* src = ei;
    const int* dst = ei + N_EDGES;

    char* p = (char*)d_ws;
    auto carve = [&](size_t bytes) -> void* {
        void* r = (void*)p;
        p += (bytes + 255) & ~(size_t)255;
        return r;
    };
    int*  counts  = (int*)carve(SCAN_N * sizeof(int));
    int*  fillpos = (int*)carve(SCAN_N * sizeof(int));
    int*  row_off = (int*)carve(SCAN_N * sizeof(int));
    int*  bsum    = (int*)carve(SCAN_BLOCKS * sizeof(int));
    int2* ep      = (int2*)carve((size_t)EP_CAP * sizeof(int2));
    unsigned* H  = (unsigned*)carve((size_t)N_NODES * 64 * sizeof(unsigned));
    unsigned* ZA = (unsigned*)carve((size_t)N_NODES * 64 * sizeof(unsigned));
    unsigned* ZB = (unsigned*)carve((size_t)N_NODES * 64 * sizeof(unsigned));

    // CSR build (per launch; deterministic work each call)
    hipMemsetAsync(counts, 0, SCAN_N * sizeof(int), stream);
    hipMemsetAsync(ep, 0, (size_t)EP_CAP * sizeof(int2), stream);  // pads -> (0,0)
    count_k<<<(N_EDGES + 255) / 256, 256, 0, stream>>>(dst, counts);
    scan1_k<<<SCAN_BLOCKS, 1024, 0, stream>>>(counts, bsum);
    scan2_k<<<1, 128, 0, stream>>>(bsum);
    scan3_k<<<SCAN_BLOCKS, 1024, 0, stream>>>(counts, bsum, row_off, fillpos);
    for (int pss = 0; pss < BUCKET_PASSES; ++pss) {
        int lo = pss * BUCKET_RANGE;
        int hi = min(N_NODES, lo + BUCKET_RANGE);
        bucket_k<<<(N_EDGES + 255) / 256, 256, 0, stream>>>(src, dst, ew,
                                                            fillpos, ep, lo, hi);
    }

    // Encoder
    encoder_k<<<512, 1024, 0, stream>>>(x, Wenc, gamma, beta, H);

    const int prop_blocks = (N_NODES + 3) / 4;   // 1 node/wave, 4 waves/block
    unsigned* bufs[2] = {ZA, ZB};
    for (int l = 0; l < NLAYERS; ++l) {
        const unsigned* zin = H;                  // x0 = H (layer input)
        for (int k = 0; k < KSTEPS; ++k) {
            int last = (k == KSTEPS - 1);
            unsigned* zout = last ? H : bufs[k & 1];
            prop_k<<<prop_blocks, 256, 0, stream>>>(zin, H, row_off, ep, zout,
                                                    last, gamma, beta);
            zin = zout;
        }
    }

    decoder_k<<<512, 1024, 0, stream>>>(H, Wdec, out);
}